// Round 3
// baseline (215.478 us; speedup 1.0000x reference)
//
#include <hip/hip_runtime.h>
#include <stdint.h>

#define B_ 2
#define T_ 2048
#define C_ 1024
#define H_ 16
#define D_ 64
// SCALE * log2(e): softmax computed in exp2 domain
#define SCALE_L2E 0.1803368801111244f

typedef unsigned short ushort_t;
typedef __attribute__((ext_vector_type(8))) __bf16 bf16x8;
typedef __attribute__((ext_vector_type(4))) float f32x4;
typedef __attribute__((ext_vector_type(4))) unsigned short ushort4_t;

__device__ __forceinline__ float bf2f(ushort_t u) {
    union { unsigned int u; float f; } v; v.u = ((unsigned int)u) << 16; return v.f;
}
__device__ __forceinline__ ushort_t f2bf(float f) {
    union { float f; unsigned int u; } v; v.f = f;
    unsigned int r = v.u + 0x7FFFu + ((v.u >> 16) & 1u);
    return (ushort_t)(r >> 16);
}

__device__ __forceinline__ void gl16(const void* g, void* l) {
    __builtin_amdgcn_global_load_lds(
        (const __attribute__((address_space(1))) void*)g,
        (__attribute__((address_space(3))) void*)l, 16, 0, 0);
}

__device__ __forceinline__ f32x4 mfma16(bf16x8 a, bf16x8 b, f32x4 c) {
    return __builtin_amdgcn_mfma_f32_16x16x32_bf16(a, b, c, 0, 0, 0);
}

// ---------------- fp32 -> bf16 convert ----------------
__global__ __launch_bounds__(256) void cvt_kernel(const float* __restrict__ in,
                                                  ushort_t* __restrict__ out, int n) {
    int stride = gridDim.x * blockDim.x;
    for (int i = blockIdx.x * blockDim.x + threadIdx.x; i * 4 < n; i += stride) {
        float4 v = *(const float4*)(in + (size_t)i * 4);
        ushort4_t o;
        o.x = f2bf(v.x); o.y = f2bf(v.y); o.z = f2bf(v.z); o.w = f2bf(v.w);
        *(ushort4_t*)(out + (size_t)i * 4) = o;
    }
}

// ---------------- GEMM: C[M,N] = A[M,K] * B[N,K]^T + bias ----------------
template <int BF16OUT>
__global__ __launch_bounds__(256) void gemm_bt(const ushort_t* __restrict__ A,
                                               const ushort_t* __restrict__ Bw,
                                               const float* __restrict__ bias,
                                               ushort_t* __restrict__ outb,
                                               float* __restrict__ outf,
                                               int M, int N, int K) {
    __shared__ ushort_t As[128 * 32];
    __shared__ ushort_t Bs[128 * 32];
    int tid = threadIdx.x, w = tid >> 6, lane = tid & 63;
    int lr = lane >> 4, lc = lane & 15;
    int wr = w >> 1, wc = w & 1;
    int row0 = blockIdx.y * 128, col0 = blockIdx.x * 128;

    f32x4 acc[4][4];
#pragma unroll
    for (int mf = 0; mf < 4; ++mf)
#pragma unroll
        for (int nf = 0; nf < 4; ++nf) acc[mf][nf] = (f32x4){0.f, 0.f, 0.f, 0.f};

    for (int k0 = 0; k0 < K; k0 += 32) {
#pragma unroll
        for (int j = 0; j < 2; ++j) {
            int idx = j * 256 + tid;
            int r = idx >> 2, c = (idx & 3) * 8;
            gl16(A + (size_t)(row0 + r) * K + k0 + c, &As[idx * 8]);
            gl16(Bw + (size_t)(col0 + r) * K + k0 + c, &Bs[idx * 8]);
        }
        __syncthreads();
        bf16x8 af[4], bfr[4];
#pragma unroll
        for (int mf = 0; mf < 4; ++mf)
            af[mf] = *(const bf16x8*)&As[(wr * 64 + mf * 16 + lc) * 32 + 8 * lr];
#pragma unroll
        for (int nf = 0; nf < 4; ++nf)
            bfr[nf] = *(const bf16x8*)&Bs[(wc * 64 + nf * 16 + lc) * 32 + 8 * lr];
#pragma unroll
        for (int mf = 0; mf < 4; ++mf)
#pragma unroll
            for (int nf = 0; nf < 4; ++nf)
                acc[mf][nf] = mfma16(af[mf], bfr[nf], acc[mf][nf]);
        __syncthreads();
    }
#pragma unroll
    for (int mf = 0; mf < 4; ++mf)
#pragma unroll
        for (int nf = 0; nf < 4; ++nf) {
            int col = col0 + wc * 64 + nf * 16 + lc;
            float bv = bias[col];
#pragma unroll
            for (int r = 0; r < 4; ++r) {
                int row = row0 + wr * 64 + mf * 16 + 4 * lr + r;
                float v = acc[mf][nf][r] + bv;
                if (BF16OUT)
                    outb[(size_t)row * N + col] = f2bf(v);
                else
                    outf[(size_t)row * N + col] = v;
            }
        }
}

// ---------------- RoPE + scatter to [B,H,T,D] (Q,K) and [B,H,D,T] (V) ----------------
__global__ __launch_bounds__(256) void rope_scatter(const ushort_t* __restrict__ qkv,
                                                    const float* __restrict__ cosT,
                                                    const float* __restrict__ sinT,
                                                    ushort_t* __restrict__ Qr,
                                                    ushort_t* __restrict__ Kr,
                                                    ushort_t* __restrict__ Vt) {
    int blk = blockIdx.x;
    int tt = blk & 31;
    int h = (blk >> 5) & 15;
    int b = blk >> 9;
    int t0 = tt * 64;
    int bh = b * H_ + h;

#pragma unroll
    for (int it = 0; it < 8; ++it) {
        int idx = it * 256 + threadIdx.x;
        int tl = idx >> 5;
        int d2 = idx & 31;
        int t = t0 + tl;
        float c = cosT[t * 32 + d2], s = sinT[t * 32 + d2];
        const ushort_t* row = &qkv[(size_t)(b * T_ + t) * 3072 + h * 64];
        float q1 = bf2f(row[2 * d2]), q2 = bf2f(row[2 * d2 + 1]);
        float k1 = bf2f(row[1024 + 2 * d2]), k2 = bf2f(row[1024 + 2 * d2 + 1]);
        size_t obase = ((size_t)bh * T_ + t) * D_;
        Qr[obase + d2] = f2bf(q1 * c - q2 * s);
        Qr[obase + d2 + 32] = f2bf(q1 * s + q2 * c);
        Kr[obase + d2] = f2bf(k1 * c - k2 * s);
        Kr[obase + d2 + 32] = f2bf(k1 * s + k2 * c);
    }
    __shared__ ushort_t vtile[64 * 64];
#pragma unroll
    for (int it = 0; it < 16; ++it) {
        int idx = it * 256 + threadIdx.x;
        int tl = idx >> 6, d = idx & 63;
        vtile[tl * 64 + d] = qkv[(size_t)(b * T_ + t0 + tl) * 3072 + 2048 + h * 64 + d];
    }
    __syncthreads();
#pragma unroll
    for (int it = 0; it < 16; ++it) {
        int idx = it * 256 + threadIdx.x;
        int d = idx >> 6, tl = idx & 63;
        Vt[((size_t)bh * D_ + d) * T_ + t0 + tl] = vtile[tl * 64 + d];
    }
}

// ---------------- causal flash attention: 1 wave per 16 q-rows ----------------
// 4096 blocks x 64 threads. No __syncthreads, no staging: K/V^T read straight
// from global (L2). Defer-max (THR=8 in exp2 domain) + end-of-loop l reduce.
__global__ __launch_bounds__(64, 4) void attn_kernel(const ushort_t* __restrict__ Qr,
                                                     const ushort_t* __restrict__ Kr,
                                                     const ushort_t* __restrict__ Vt,
                                                     ushort_t* __restrict__ attnb) {
    int id = blockIdx.x;
    // XCD-clustered mapping (blocks round-robin XCDs by id&7), per-CU length mix
    int x = id & 7;
    int c = (id >> 3) & 31;
    int s = id >> 8;           // 0..15
    int bl = s >> 2;           // 0..3
    int bh = x * 4 + bl;
    int cc;
    if (bl == 0) cc = c;
    else if (bl == 1) cc = 31 - c;
    else if (bl == 2) cc = (c + 16) & 31;
    else cc = 31 - ((c + 16) & 31);
    int qtile = 4 * cc + (s & 3);   // 0..127 (16-row q tiles)
    int b = bh >> 4, h = bh & 15;

    const ushort_t* Qp = Qr + (size_t)bh * T_ * D_;
    const ushort_t* Kp = Kr + (size_t)bh * T_ * D_;
    const ushort_t* Vp = Vt + (size_t)bh * D_ * T_;
    int lane = threadIdx.x & 63;
    int lr = lane >> 4, lc = lane & 15;

    __shared__ ushort_t Ps[16 * 64];

    int qrow = qtile * 16 + lc;
    bf16x8 qf0 = *(const bf16x8*)(Qp + (size_t)qrow * D_ + 8 * lr);
    bf16x8 qf1 = *(const bf16x8*)(Qp + (size_t)qrow * D_ + 32 + 8 * lr);

    float m_st[4], l_loc[4];
    f32x4 acc[4];
#pragma unroll
    for (int r = 0; r < 4; ++r) { m_st[r] = -1e30f; l_loc[r] = 0.f; }
#pragma unroll
    for (int f = 0; f < 4; ++f) acc[f] = (f32x4){0.f, 0.f, 0.f, 0.f};

    int qg = qtile * 16 + 4 * lr;
    int dkt = qtile >> 2;          // diagonal 64-col tile index
    int nkt = dkt + 1;

    for (int kt = 0; kt < nkt; ++kt) {
        int t0 = kt * 64;

        // S = Q K^T, K fragments straight from global (L2)
        f32x4 sv[4];
        __builtin_amdgcn_s_setprio(1);
#pragma unroll
        for (int f = 0; f < 4; ++f) {
            sv[f] = (f32x4){0.f, 0.f, 0.f, 0.f};
#pragma unroll
            for (int kk = 0; kk < 2; ++kk) {
                bf16x8 kf = *(const bf16x8*)(Kp + (size_t)(t0 + 16 * f + lc) * D_ + 32 * kk + 8 * lr);
                sv[f] = mfma16(kk ? qf1 : qf0, kf, sv[f]);
            }
        }
        __builtin_amdgcn_s_setprio(0);

        // scale (exp2 domain) + causal mask (diag tile only) + per-lane max
        float lmax[4] = {-1e30f, -1e30f, -1e30f, -1e30f};
        if (kt == dkt) {
#pragma unroll
            for (int f = 0; f < 4; ++f) {
                int kcol = t0 + 16 * f + lc;
#pragma unroll
                for (int r = 0; r < 4; ++r) {
                    float v = sv[f][r] * SCALE_L2E;
                    v = (kcol > qg + r) ? -1e30f : v;
                    sv[f][r] = v;
                    lmax[r] = fmaxf(lmax[r], v);
                }
            }
        } else {
#pragma unroll
            for (int f = 0; f < 4; ++f)
#pragma unroll
                for (int r = 0; r < 4; ++r) {
                    float v = sv[f][r] * SCALE_L2E;
                    sv[f][r] = v;
                    lmax[r] = fmaxf(lmax[r], v);
                }
        }

        // defer-max: only take the reduce+rescale path when some row grew past m+8
        float dmax = fmaxf(fmaxf(lmax[0] - m_st[0], lmax[1] - m_st[1]),
                           fmaxf(lmax[2] - m_st[2], lmax[3] - m_st[3]));
        if (!__all(dmax <= 8.0f)) {
            float tmax[4] = {lmax[0], lmax[1], lmax[2], lmax[3]};
#pragma unroll
            for (int off = 1; off < 16; off <<= 1)
#pragma unroll
                for (int r = 0; r < 4; ++r)
                    tmax[r] = fmaxf(tmax[r], __shfl_xor(tmax[r], off, 64));
#pragma unroll
            for (int r = 0; r < 4; ++r) {
                float mn = fmaxf(m_st[r], tmax[r]);
                float alpha = exp2f(m_st[r] - mn);
                m_st[r] = mn;
                l_loc[r] *= alpha;
#pragma unroll
                for (int f = 0; f < 4; ++f) acc[f][r] *= alpha;
            }
        }

        // P = exp2(s - m), accumulate per-lane row-sums, write P to wave-private LDS
#pragma unroll
        for (int f = 0; f < 4; ++f)
#pragma unroll
            for (int r = 0; r < 4; ++r) {
                float p = exp2f(sv[f][r] - m_st[r]);
                l_loc[r] += p;
                int prow = 4 * lr + r, pcol = 16 * f + lc;
                Ps[prow * 64 + ((((pcol >> 3) ^ (prow & 7))) * 8) + (pcol & 7)] = f2bf(p);
            }

        // PV: P from LDS (swizzled), V^T fragments straight from global (L2)
        __builtin_amdgcn_s_setprio(1);
#pragma unroll
        for (int kk = 0; kk < 2; ++kk) {
            bf16x8 pf = *(const bf16x8*)&Ps[lc * 64 + (((lr + 4 * kk) ^ (lc & 7)) * 8)];
#pragma unroll
            for (int f = 0; f < 4; ++f) {
                bf16x8 vfr = *(const bf16x8*)(Vp + (size_t)(16 * f + lc) * T_ + t0 + 32 * kk + 8 * lr);
                acc[f] = mfma16(pf, vfr, acc[f]);
            }
        }
        __builtin_amdgcn_s_setprio(0);
    }

    // single end-of-loop row-sum reduce
#pragma unroll
    for (int off = 1; off < 16; off <<= 1)
#pragma unroll
        for (int r = 0; r < 4; ++r) l_loc[r] += __shfl_xor(l_loc[r], off, 64);
#pragma unroll
    for (int r = 0; r < 4; ++r) l_loc[r] = 1.f / l_loc[r];

#pragma unroll
    for (int f = 0; f < 4; ++f)
#pragma unroll
        for (int r = 0; r < 4; ++r) {
            int t = qtile * 16 + 4 * lr + r;
            attnb[((size_t)(b * T_ + t)) * 1024 + h * 64 + 16 * f + lc] = f2bf(acc[f][r] * l_loc[r]);
        }
}

extern "C" void kernel_launch(void* const* d_in, const int* in_sizes, int n_in,
                              void* d_out, int out_size, void* d_ws, size_t ws_size,
                              hipStream_t stream) {
    const float* hs     = (const float*)d_in[0];
    const float* cosp   = (const float*)d_in[1];
    const float* sinp   = (const float*)d_in[2];
    const float* qkv_w  = (const float*)d_in[3];
    const float* qkv_b  = (const float*)d_in[4];
    const float* proj_w = (const float*)d_in[5];
    const float* proj_b = (const float*)d_in[6];
    float* out = (float*)d_out;

    const int M = B_ * T_;            // 4096
    ushort_t* Xb     = (ushort_t*)d_ws;
    ushort_t* Wqkvb  = Xb + (size_t)M * C_;
    ushort_t* Wprojb = Wqkvb + (size_t)3072 * C_;
    ushort_t* QKV    = Wprojb + (size_t)C_ * C_;
    ushort_t* Qr     = QKV + (size_t)M * 3072;
    ushort_t* Kr     = Qr + (size_t)B_ * H_ * T_ * D_;
    ushort_t* Vt     = Kr + (size_t)B_ * H_ * T_ * D_;
    ushort_t* attnb  = Vt + (size_t)B_ * H_ * T_ * D_;

    cvt_kernel<<<1024, 256, 0, stream>>>(hs, Xb, M * C_);
    cvt_kernel<<<1024, 256, 0, stream>>>(qkv_w, Wqkvb, 3072 * C_);
    cvt_kernel<<<256, 256, 0, stream>>>(proj_w, Wprojb, C_ * C_);

    gemm_bt<1><<<dim3(3072 / 128, M / 128), 256, 0, stream>>>(
        Xb, Wqkvb, qkv_b, QKV, nullptr, M, 3072, C_);

    rope_scatter<<<B_ * H_ * (T_ / 64), 256, 0, stream>>>(QKV, cosp, sinp, Qr, Kr, Vt);

    attn_kernel<<<4096, 64, 0, stream>>>(Qr, Kr, Vt, attnb);

    gemm_bt<0><<<dim3(1024 / 128, M / 128), 256, 0, stream>>>(
        attnb, Wprojb, proj_b, nullptr, out, M, C_, C_);
}

// Round 4
// 144.544 us; speedup vs baseline: 1.4907x; 1.4907x over previous
//
#include <hip/hip_runtime.h>
#include <stdint.h>

#define B_ 2
#define T_ 2048
#define C_ 1024
#define H_ 16
#define D_ 64
// SCALE * log2(e): softmax computed in exp2 domain; folded into Q at rope time
#define SCALE_L2E 0.1803368801111244f

typedef unsigned short ushort_t;
typedef __attribute__((ext_vector_type(8))) __bf16 bf16x8;
typedef __attribute__((ext_vector_type(4))) float f32x4;
typedef __attribute__((ext_vector_type(4))) unsigned short ushort4_t;

__device__ __forceinline__ float bf2f(ushort_t u) {
    union { unsigned int u; float f; } v; v.u = ((unsigned int)u) << 16; return v.f;
}
__device__ __forceinline__ ushort_t f2bf(float f) {
    union { float f; unsigned int u; } v; v.f = f;
    unsigned int r = v.u + 0x7FFFu + ((v.u >> 16) & 1u);
    return (ushort_t)(r >> 16);
}

__device__ __forceinline__ void gl16(const void* g, void* l) {
    __builtin_amdgcn_global_load_lds(
        (const __attribute__((address_space(1))) void*)g,
        (__attribute__((address_space(3))) void*)l, 16, 0, 0);
}

__device__ __forceinline__ f32x4 mfma16(bf16x8 a, bf16x8 b, f32x4 c) {
    return __builtin_amdgcn_mfma_f32_16x16x32_bf16(a, b, c, 0, 0, 0);
}

// ---------------- fp32 -> bf16 convert ----------------
__global__ __launch_bounds__(256) void cvt_kernel(const float* __restrict__ in,
                                                  ushort_t* __restrict__ out, int n) {
    int stride = gridDim.x * blockDim.x;
    for (int i = blockIdx.x * blockDim.x + threadIdx.x; i * 4 < n; i += stride) {
        float4 v = *(const float4*)(in + (size_t)i * 4);
        ushort4_t o;
        o.x = f2bf(v.x); o.y = f2bf(v.y); o.z = f2bf(v.z); o.w = f2bf(v.w);
        *(ushort4_t*)(out + (size_t)i * 4) = o;
    }
}

// ---------------- GEMM: C[M,N] = A[M,K] * B[N,K]^T + bias ----------------
template <int BF16OUT>
__global__ __launch_bounds__(256) void gemm_bt(const ushort_t* __restrict__ A,
                                               const ushort_t* __restrict__ Bw,
                                               const float* __restrict__ bias,
                                               ushort_t* __restrict__ outb,
                                               float* __restrict__ outf,
                                               int M, int N, int K) {
    __shared__ ushort_t As[128 * 32];
    __shared__ ushort_t Bs[128 * 32];
    int tid = threadIdx.x, w = tid >> 6, lane = tid & 63;
    int lr = lane >> 4, lc = lane & 15;
    int wr = w >> 1, wc = w & 1;
    int row0 = blockIdx.y * 128, col0 = blockIdx.x * 128;

    f32x4 acc[4][4];
#pragma unroll
    for (int mf = 0; mf < 4; ++mf)
#pragma unroll
        for (int nf = 0; nf < 4; ++nf) acc[mf][nf] = (f32x4){0.f, 0.f, 0.f, 0.f};

    for (int k0 = 0; k0 < K; k0 += 32) {
#pragma unroll
        for (int j = 0; j < 2; ++j) {
            int idx = j * 256 + tid;
            int r = idx >> 2, c = (idx & 3) * 8;
            gl16(A + (size_t)(row0 + r) * K + k0 + c, &As[idx * 8]);
            gl16(Bw + (size_t)(col0 + r) * K + k0 + c, &Bs[idx * 8]);
        }
        __syncthreads();
        bf16x8 af[4], bfr[4];
#pragma unroll
        for (int mf = 0; mf < 4; ++mf)
            af[mf] = *(const bf16x8*)&As[(wr * 64 + mf * 16 + lc) * 32 + 8 * lr];
#pragma unroll
        for (int nf = 0; nf < 4; ++nf)
            bfr[nf] = *(const bf16x8*)&Bs[(wc * 64 + nf * 16 + lc) * 32 + 8 * lr];
#pragma unroll
        for (int mf = 0; mf < 4; ++mf)
#pragma unroll
            for (int nf = 0; nf < 4; ++nf)
                acc[mf][nf] = mfma16(af[mf], bfr[nf], acc[mf][nf]);
        __syncthreads();
    }
#pragma unroll
    for (int mf = 0; mf < 4; ++mf)
#pragma unroll
        for (int nf = 0; nf < 4; ++nf) {
            int col = col0 + wc * 64 + nf * 16 + lc;
            float bv = bias[col];
#pragma unroll
            for (int r = 0; r < 4; ++r) {
                int row = row0 + wr * 64 + mf * 16 + 4 * lr + r;
                float v = acc[mf][nf][r] + bv;
                if (BF16OUT)
                    outb[(size_t)row * N + col] = f2bf(v);
                else
                    outf[(size_t)row * N + col] = v;
            }
        }
}

// ---------------- RoPE + scatter; Q pre-scaled by SCALE*log2(e) ----------------
__global__ __launch_bounds__(256) void rope_scatter(const ushort_t* __restrict__ qkv,
                                                    const float* __restrict__ cosT,
                                                    const float* __restrict__ sinT,
                                                    ushort_t* __restrict__ Qr,
                                                    ushort_t* __restrict__ Kr,
                                                    ushort_t* __restrict__ Vt) {
    int blk = blockIdx.x;
    int tt = blk & 31;
    int h = (blk >> 5) & 15;
    int b = blk >> 9;
    int t0 = tt * 64;
    int bh = b * H_ + h;

#pragma unroll
    for (int it = 0; it < 8; ++it) {
        int idx = it * 256 + threadIdx.x;
        int tl = idx >> 5;
        int d2 = idx & 31;
        int t = t0 + tl;
        float c = cosT[t * 32 + d2], s = sinT[t * 32 + d2];
        const ushort_t* row = &qkv[(size_t)(b * T_ + t) * 3072 + h * 64];
        float q1 = bf2f(row[2 * d2]), q2 = bf2f(row[2 * d2 + 1]);
        float k1 = bf2f(row[1024 + 2 * d2]), k2 = bf2f(row[1024 + 2 * d2 + 1]);
        size_t obase = ((size_t)bh * T_ + t) * D_;
        Qr[obase + d2] = f2bf((q1 * c - q2 * s) * SCALE_L2E);
        Qr[obase + d2 + 32] = f2bf((q1 * s + q2 * c) * SCALE_L2E);
        Kr[obase + d2] = f2bf(k1 * c - k2 * s);
        Kr[obase + d2 + 32] = f2bf(k1 * s + k2 * c);
    }
    __shared__ ushort_t vtile[64 * 64];
#pragma unroll
    for (int it = 0; it < 16; ++it) {
        int idx = it * 256 + threadIdx.x;
        int tl = idx >> 6, d = idx & 63;
        vtile[tl * 64 + d] = qkv[(size_t)(b * T_ + t0 + tl) * 3072 + 2048 + h * 64 + d];
    }
    __syncthreads();
#pragma unroll
    for (int it = 0; it < 16; ++it) {
        int idx = it * 256 + threadIdx.x;
        int d = idx >> 6, tl = idx & 63;
        Vt[((size_t)bh * D_ + d) * T_ + t0 + tl] = vtile[tl * 64 + d];
    }
}

// ---------------- causal flash attention, staged + dbuf, paired q-tiles ----------------
// grid: 512 blocks (id = i*32 + bh, i in [0,16)); block does q-tile i then 31-i
// => exactly 33 kv-tile iterations per block, XCD = bh%8 (L2 K/V partitioning).
__global__ __launch_bounds__(256) void attn_kernel(const ushort_t* __restrict__ Qr,
                                                   const ushort_t* __restrict__ Kr,
                                                   const ushort_t* __restrict__ Vt,
                                                   ushort_t* __restrict__ attnb) {
    int id = blockIdx.x;
    int bh = id & 31;
    int i_ = id >> 5;
    int b = bh >> 4, h = bh & 15;

    const ushort_t* Qp = Qr + (size_t)bh * T_ * D_;
    const ushort_t* Kp = Kr + (size_t)bh * T_ * D_;
    const ushort_t* Vp = Vt + (size_t)bh * D_ * T_;
    int tid = threadIdx.x, w = tid >> 6, lane = tid & 63;
    int lr = lane >> 4, lc = lane & 15;

    __shared__ ushort_t Ks[2][64 * 64];
    __shared__ ushort_t Vs[2][64 * 64];
    __shared__ ushort_t Ps[4][16 * 64];

    auto stage = [&](int buf, int kt) {
        int t0 = kt * 64;
#pragma unroll
        for (int j = 0; j < 2; ++j) {
            int idx = j * 256 + tid;
            int row = idx >> 3, ch = idx & 7;
            int sch = ch ^ (row & 7);
            gl16(Kp + (size_t)(t0 + row) * D_ + sch * 8, &Ks[buf][idx * 8]);
            gl16(Vp + (size_t)row * T_ + t0 + sch * 8, &Vs[buf][idx * 8]);
        }
    };

#pragma unroll 1
    for (int pass = 0; pass < 2; ++pass) {
        int qt = pass ? (31 - i_) : i_;

        int qrow = qt * 64 + w * 16 + lc;
        bf16x8 qf0 = *(const bf16x8*)(Qp + (size_t)qrow * D_ + 8 * lr);
        bf16x8 qf1 = *(const bf16x8*)(Qp + (size_t)qrow * D_ + 32 + 8 * lr);

        float m_st[4], l_loc[4];
        f32x4 acc[4];
#pragma unroll
        for (int r = 0; r < 4; ++r) { m_st[r] = -1e30f; l_loc[r] = 0.f; }
#pragma unroll
        for (int f = 0; f < 4; ++f) acc[f] = (f32x4){0.f, 0.f, 0.f, 0.f};

        int qg = qt * 64 + w * 16 + 4 * lr;

        stage(0, 0);
        asm volatile("s_waitcnt vmcnt(0)" ::: "memory");
        __builtin_amdgcn_s_barrier();

        for (int kt = 0; kt <= qt; ++kt) {
            int cur = kt & 1;
            if (kt < qt) stage(cur ^ 1, kt + 1);
            int t0 = kt * 64;

            // S = Q K^T (Q pre-scaled into exp2 domain)
            f32x4 sv[4];
            __builtin_amdgcn_s_setprio(1);
#pragma unroll
            for (int f = 0; f < 4; ++f) {
                sv[f] = (f32x4){0.f, 0.f, 0.f, 0.f};
                int row = 16 * f + lc;
#pragma unroll
                for (int kk = 0; kk < 2; ++kk) {
                    bf16x8 kf = *(const bf16x8*)&Ks[cur][row * 64 + (((lr + 4 * kk) ^ (row & 7)) * 8)];
                    sv[f] = mfma16(kk ? qf1 : qf0, kf, sv[f]);
                }
            }
            __builtin_amdgcn_s_setprio(0);

            // causal mask (diag tile only) + per-lane row max
            float lmax[4] = {-1e30f, -1e30f, -1e30f, -1e30f};
            if (kt == qt) {
#pragma unroll
                for (int f = 0; f < 4; ++f) {
                    int kcol = t0 + 16 * f + lc;
#pragma unroll
                    for (int r = 0; r < 4; ++r) {
                        float v = sv[f][r];
                        v = (kcol > qg + r) ? -1e30f : v;
                        sv[f][r] = v;
                        lmax[r] = fmaxf(lmax[r], v);
                    }
                }
            } else {
#pragma unroll
                for (int f = 0; f < 4; ++f)
#pragma unroll
                    for (int r = 0; r < 4; ++r) {
                        lmax[r] = fmaxf(lmax[r], sv[f][r]);
                    }
            }

            // defer-max: reduce+rescale only when a row grew past m+8 (exp2 domain)
            float dmax = fmaxf(fmaxf(lmax[0] - m_st[0], lmax[1] - m_st[1]),
                               fmaxf(lmax[2] - m_st[2], lmax[3] - m_st[3]));
            if (!__all(dmax <= 8.0f)) {
                float tmax[4] = {lmax[0], lmax[1], lmax[2], lmax[3]};
#pragma unroll
                for (int off = 1; off < 16; off <<= 1)
#pragma unroll
                    for (int r = 0; r < 4; ++r)
                        tmax[r] = fmaxf(tmax[r], __shfl_xor(tmax[r], off, 64));
#pragma unroll
                for (int r = 0; r < 4; ++r) {
                    float mn = fmaxf(m_st[r], tmax[r]);
                    float alpha = exp2f(m_st[r] - mn);
                    m_st[r] = mn;
                    l_loc[r] *= alpha;
#pragma unroll
                    for (int f = 0; f < 4; ++f) acc[f][r] *= alpha;
                }
            }

            // P = exp2(s - m); per-lane row-sum accumulate; P -> wave-private LDS
#pragma unroll
            for (int f = 0; f < 4; ++f)
#pragma unroll
                for (int r = 0; r < 4; ++r) {
                    float p = exp2f(sv[f][r] - m_st[r]);
                    l_loc[r] += p;
                    int prow = 4 * lr + r, pcol = 16 * f + lc;
                    Ps[w][prow * 64 + (((pcol >> 3) ^ (prow & 7)) * 8) + (pcol & 7)] = f2bf(p);
                }

            // PV
            __builtin_amdgcn_s_setprio(1);
#pragma unroll
            for (int kk = 0; kk < 2; ++kk) {
                bf16x8 pf = *(const bf16x8*)&Ps[w][lc * 64 + (((lr + 4 * kk) ^ (lc & 7)) * 8)];
#pragma unroll
                for (int f = 0; f < 4; ++f) {
                    int vrow = 16 * f + lc;
                    bf16x8 vfr = *(const bf16x8*)&Vs[cur][vrow * 64 + (((lr + 4 * kk) ^ (vrow & 7)) * 8)];
                    acc[f] = mfma16(pf, vfr, acc[f]);
                }
            }
            __builtin_amdgcn_s_setprio(0);

            asm volatile("s_waitcnt vmcnt(0)" ::: "memory");
            __builtin_amdgcn_s_barrier();
        }

        // end-of-pass l reduce + store
#pragma unroll
        for (int off = 1; off < 16; off <<= 1)
#pragma unroll
            for (int r = 0; r < 4; ++r) l_loc[r] += __shfl_xor(l_loc[r], off, 64);
#pragma unroll
        for (int r = 0; r < 4; ++r) l_loc[r] = 1.f / l_loc[r];
#pragma unroll
        for (int f = 0; f < 4; ++f)
#pragma unroll
            for (int r = 0; r < 4; ++r) {
                int t = qt * 64 + w * 16 + 4 * lr + r;
                attnb[((size_t)(b * T_ + t)) * 1024 + h * 64 + 16 * f + lc] =
                    f2bf(acc[f][r] * l_loc[r]);
            }
    }
}

extern "C" void kernel_launch(void* const* d_in, const int* in_sizes, int n_in,
                              void* d_out, int out_size, void* d_ws, size_t ws_size,
                              hipStream_t stream) {
    const float* hs     = (const float*)d_in[0];
    const float* cosp   = (const float*)d_in[1];
    const float* sinp   = (const float*)d_in[2];
    const float* qkv_w  = (const float*)d_in[3];
    const float* qkv_b  = (const float*)d_in[4];
    const float* proj_w = (const float*)d_in[5];
    const float* proj_b = (const float*)d_in[6];
    float* out = (float*)d_out;

    const int M = B_ * T_;            // 4096
    ushort_t* Xb     = (ushort_t*)d_ws;
    ushort_t* Wqkvb  = Xb + (size_t)M * C_;
    ushort_t* Wprojb = Wqkvb + (size_t)3072 * C_;
    ushort_t* QKV    = Wprojb + (size_t)C_ * C_;
    ushort_t* Qr     = QKV + (size_t)M * 3072;
    ushort_t* Kr     = Qr + (size_t)B_ * H_ * T_ * D_;
    ushort_t* Vt     = Kr + (size_t)B_ * H_ * T_ * D_;
    ushort_t* attnb  = Vt + (size_t)B_ * H_ * T_ * D_;

    cvt_kernel<<<1024, 256, 0, stream>>>(hs, Xb, M * C_);
    cvt_kernel<<<1024, 256, 0, stream>>>(qkv_w, Wqkvb, 3072 * C_);
    cvt_kernel<<<256, 256, 0, stream>>>(proj_w, Wprojb, C_ * C_);

    gemm_bt<1><<<dim3(3072 / 128, M / 128), 256, 0, stream>>>(
        Xb, Wqkvb, qkv_b, QKV, nullptr, M, 3072, C_);

    rope_scatter<<<B_ * H_ * (T_ / 64), 256, 0, stream>>>(QKV, cosp, sinp, Qr, Kr, Vt);

    attn_kernel<<<512, 256, 0, stream>>>(Qr, Kr, Vt, attnb);

    gemm_bt<0><<<dim3(1024 / 128, M / 128), 256, 0, stream>>>(
        attnb, Wprojb, proj_b, nullptr, out, M, C_, C_);
}

// Round 5
// 138.256 us; speedup vs baseline: 1.5585x; 1.0455x over previous
//
#include <hip/hip_runtime.h>
#include <stdint.h>

#define B_ 2
#define T_ 2048
#define C_ 1024
#define H_ 16
#define D_ 64
// SCALE * log2(e): softmax computed in exp2 domain; folded into Q at rope time
#define SCALE_L2E 0.1803368801111244f

typedef unsigned short ushort_t;
typedef __attribute__((ext_vector_type(8))) __bf16 bf16x8;
typedef __attribute__((ext_vector_type(4))) float f32x4;
typedef __attribute__((ext_vector_type(4))) unsigned short ushort4_t;

__device__ __forceinline__ float bf2f(ushort_t u) {
    union { unsigned int u; float f; } v; v.u = ((unsigned int)u) << 16; return v.f;
}
// native f32->bf16 (compiler emits v_cvt_pk_bf16_f32, RNE)
__device__ __forceinline__ ushort_t f2bf(float f) {
    union { __bf16 h; ushort_t u; } v; v.h = (__bf16)f; return v.u;
}

__device__ __forceinline__ void gl16(const void* g, void* l) {
    __builtin_amdgcn_global_load_lds(
        (const __attribute__((address_space(1))) void*)g,
        (__attribute__((address_space(3))) void*)l, 16, 0, 0);
}

__device__ __forceinline__ f32x4 mfma16(bf16x8 a, bf16x8 b, f32x4 c) {
    return __builtin_amdgcn_mfma_f32_16x16x32_bf16(a, b, c, 0, 0, 0);
}

// ---------------- fused fp32 -> bf16 convert (3 tensors) ----------------
__global__ __launch_bounds__(256) void cvt3_kernel(const float* __restrict__ a, ushort_t* __restrict__ oa, int na,
                                                   const float* __restrict__ b, ushort_t* __restrict__ ob, int nb,
                                                   const float* __restrict__ c, ushort_t* __restrict__ oc, int nc) {
    int total4 = (na + nb + nc) >> 2;
    int stride = gridDim.x * blockDim.x;
    for (int i = blockIdx.x * blockDim.x + threadIdx.x; i < total4; i += stride) {
        int e = i << 2;
        const float* src; ushort_t* dst; int off;
        if (e < na) { src = a; dst = oa; off = e; }
        else if (e < na + nb) { src = b; dst = ob; off = e - na; }
        else { src = c; dst = oc; off = e - na - nb; }
        float4 v = *(const float4*)(src + off);
        ushort4_t o;
        o.x = f2bf(v.x); o.y = f2bf(v.y); o.z = f2bf(v.z); o.w = f2bf(v.w);
        *(ushort4_t*)(dst + off) = o;
    }
}

// ---------------- GEMM: C[M,N] = A[M,K] * B[N,K]^T + bias ----------------
// 1-D grid with bijective XCD swizzle (grid % 8 == 0).
template <int BF16OUT>
__global__ __launch_bounds__(256) void gemm_bt(const ushort_t* __restrict__ A,
                                               const ushort_t* __restrict__ Bw,
                                               const float* __restrict__ bias,
                                               ushort_t* __restrict__ outb,
                                               float* __restrict__ outf,
                                               int M, int N, int K, int nxt) {
    int nwg = gridDim.x;
    int q = nwg >> 3;
    int nid = (blockIdx.x & 7) * q + (blockIdx.x >> 3);
    int bx = nid % nxt, by = nid / nxt;

    __shared__ ushort_t As[128 * 32];
    __shared__ ushort_t Bs[128 * 32];
    int tid = threadIdx.x, w = tid >> 6, lane = tid & 63;
    int lr = lane >> 4, lc = lane & 15;
    int wr = w >> 1, wc = w & 1;
    int row0 = by * 128, col0 = bx * 128;

    f32x4 acc[4][4];
#pragma unroll
    for (int mf = 0; mf < 4; ++mf)
#pragma unroll
        for (int nf = 0; nf < 4; ++nf) acc[mf][nf] = (f32x4){0.f, 0.f, 0.f, 0.f};

    for (int k0 = 0; k0 < K; k0 += 32) {
#pragma unroll
        for (int j = 0; j < 2; ++j) {
            int idx = j * 256 + tid;
            int r = idx >> 2, c = (idx & 3) * 8;
            gl16(A + (size_t)(row0 + r) * K + k0 + c, &As[idx * 8]);
            gl16(Bw + (size_t)(col0 + r) * K + k0 + c, &Bs[idx * 8]);
        }
        __syncthreads();
        bf16x8 af[4], bfr[4];
#pragma unroll
        for (int mf = 0; mf < 4; ++mf)
            af[mf] = *(const bf16x8*)&As[(wr * 64 + mf * 16 + lc) * 32 + 8 * lr];
#pragma unroll
        for (int nf = 0; nf < 4; ++nf)
            bfr[nf] = *(const bf16x8*)&Bs[(wc * 64 + nf * 16 + lc) * 32 + 8 * lr];
#pragma unroll
        for (int mf = 0; mf < 4; ++mf)
#pragma unroll
            for (int nf = 0; nf < 4; ++nf)
                acc[mf][nf] = mfma16(af[mf], bfr[nf], acc[mf][nf]);
        __syncthreads();
    }
#pragma unroll
    for (int mf = 0; mf < 4; ++mf)
#pragma unroll
        for (int nf = 0; nf < 4; ++nf) {
            int col = col0 + wc * 64 + nf * 16 + lc;
            float bv = bias[col];
#pragma unroll
            for (int r = 0; r < 4; ++r) {
                int row = row0 + wr * 64 + mf * 16 + 4 * lr + r;
                float v = acc[mf][nf][r] + bv;
                if (BF16OUT)
                    outb[(size_t)row * N + col] = f2bf(v);
                else
                    outf[(size_t)row * N + col] = v;
            }
        }
}

// ---------------- RoPE + scatter; Q pre-scaled by SCALE*log2(e) ----------------
__global__ __launch_bounds__(256) void rope_scatter(const ushort_t* __restrict__ qkv,
                                                    const float* __restrict__ cosT,
                                                    const float* __restrict__ sinT,
                                                    ushort_t* __restrict__ Qr,
                                                    ushort_t* __restrict__ Kr,
                                                    ushort_t* __restrict__ Vt) {
    int blk = blockIdx.x;
    int tt = blk & 31;
    int h = (blk >> 5) & 15;
    int b = blk >> 9;
    int t0 = tt * 64;
    int bh = b * H_ + h;

#pragma unroll
    for (int it = 0; it < 8; ++it) {
        int idx = it * 256 + threadIdx.x;
        int tl = idx >> 5;
        int d2 = idx & 31;
        int t = t0 + tl;
        float c = cosT[t * 32 + d2], s = sinT[t * 32 + d2];
        const ushort_t* row = &qkv[(size_t)(b * T_ + t) * 3072 + h * 64];
        float q1 = bf2f(row[2 * d2]), q2 = bf2f(row[2 * d2 + 1]);
        float k1 = bf2f(row[1024 + 2 * d2]), k2 = bf2f(row[1024 + 2 * d2 + 1]);
        size_t obase = ((size_t)bh * T_ + t) * D_;
        Qr[obase + d2] = f2bf((q1 * c - q2 * s) * SCALE_L2E);
        Qr[obase + d2 + 32] = f2bf((q1 * s + q2 * c) * SCALE_L2E);
        Kr[obase + d2] = f2bf(k1 * c - k2 * s);
        Kr[obase + d2 + 32] = f2bf(k1 * s + k2 * c);
    }
    __shared__ ushort_t vtile[64 * 64];
#pragma unroll
    for (int it = 0; it < 16; ++it) {
        int idx = it * 256 + threadIdx.x;
        int tl = idx >> 6, d = idx & 63;
        vtile[tl * 64 + d] = qkv[(size_t)(b * T_ + t0 + tl) * 3072 + 2048 + h * 64 + d];
    }
    __syncthreads();
#pragma unroll
    for (int it = 0; it < 16; ++it) {
        int idx = it * 256 + threadIdx.x;
        int d = idx >> 6, tl = idx & 63;
        Vt[((size_t)bh * D_ + d) * T_ + t0 + tl] = vtile[tl * 64 + d];
    }
}

// ---------------- causal flash attention, staged + dbuf, paired q-tiles ----------------
// grid: 512 blocks (id = i*32 + bh); block does q-tile i then 31-i => 33 kv-iters.
// l computed by ones-column MFMA; -m folded into QK accumulator init; defer-max.
__global__ __launch_bounds__(256) void attn_kernel(const ushort_t* __restrict__ Qr,
                                                   const ushort_t* __restrict__ Kr,
                                                   const ushort_t* __restrict__ Vt,
                                                   ushort_t* __restrict__ attnb) {
    int id = blockIdx.x;
    int bh = id & 31;
    int i_ = id >> 5;
    int b = bh >> 4, h = bh & 15;

    const ushort_t* Qp = Qr + (size_t)bh * T_ * D_;
    const ushort_t* Kp = Kr + (size_t)bh * T_ * D_;
    const ushort_t* Vp = Vt + (size_t)bh * D_ * T_;
    int tid = threadIdx.x, w = tid >> 6, lane = tid & 63;
    int lr = lane >> 4, lc = lane & 15;

    __shared__ ushort_t Ks[2][64 * 64];
    __shared__ ushort_t Vs[2][64 * 64];
    __shared__ ushort_t Ps[4][16 * 64];

    bf16x8 ones;
#pragma unroll
    for (int i = 0; i < 8; ++i) ones[i] = (__bf16)1.0f;

    auto stage = [&](int buf, int kt) {
        int t0 = kt * 64;
#pragma unroll
        for (int j = 0; j < 2; ++j) {
            int idx = j * 256 + tid;
            int row = idx >> 3, ch = idx & 7;
            int sch = ch ^ (row & 7);
            gl16(Kp + (size_t)(t0 + row) * D_ + sch * 8, &Ks[buf][idx * 8]);
            gl16(Vp + (size_t)row * T_ + t0 + sch * 8, &Vs[buf][idx * 8]);
        }
    };

#pragma unroll 1
    for (int pass = 0; pass < 2; ++pass) {
        int qt = pass ? (31 - i_) : i_;

        int qrow = qt * 64 + w * 16 + lc;
        bf16x8 qf0 = *(const bf16x8*)(Qp + (size_t)qrow * D_ + 8 * lr);
        bf16x8 qf1 = *(const bf16x8*)(Qp + (size_t)qrow * D_ + 32 + 8 * lr);

        float m_st[4];
        f32x4 acc[4], acc_l;
#pragma unroll
        for (int r = 0; r < 4; ++r) m_st[r] = 0.f;
#pragma unroll
        for (int f = 0; f < 4; ++f) acc[f] = (f32x4){0.f, 0.f, 0.f, 0.f};
        acc_l = (f32x4){0.f, 0.f, 0.f, 0.f};

        int qg = qt * 64 + w * 16 + 4 * lr;

        stage(0, 0);
        asm volatile("s_waitcnt vmcnt(0)" ::: "memory");
        __builtin_amdgcn_s_barrier();

        for (int kt = 0; kt <= qt; ++kt) {
            int cur = kt & 1;
            if (kt < qt) stage(cur ^ 1, kt + 1);
            int t0 = kt * 64;

            // S - m_old = Q K^T with C-init = -m_old (Q pre-scaled to exp2 domain)
            f32x4 neg_m = (f32x4){-m_st[0], -m_st[1], -m_st[2], -m_st[3]};
            f32x4 sv[4];
            __builtin_amdgcn_s_setprio(1);
#pragma unroll
            for (int f = 0; f < 4; ++f) {
                sv[f] = neg_m;
                int row = 16 * f + lc;
#pragma unroll
                for (int kk = 0; kk < 2; ++kk) {
                    bf16x8 kf = *(const bf16x8*)&Ks[cur][row * 64 + (((lr + 4 * kk) ^ (row & 7)) * 8)];
                    sv[f] = mfma16(kk ? qf1 : qf0, kf, sv[f]);
                }
            }
            __builtin_amdgcn_s_setprio(0);

            // causal mask (diag tile only) + per-lane row max of (S - m_old)
            float lmax[4] = {-1e30f, -1e30f, -1e30f, -1e30f};
            if (kt == qt) {
#pragma unroll
                for (int f = 0; f < 4; ++f) {
                    int kcol = t0 + 16 * f + lc;
#pragma unroll
                    for (int r = 0; r < 4; ++r) {
                        float v = sv[f][r];
                        v = (kcol > qg + r) ? -1e30f : v;
                        sv[f][r] = v;
                        lmax[r] = fmaxf(lmax[r], v);
                    }
                }
            } else {
#pragma unroll
                for (int f = 0; f < 4; ++f)
#pragma unroll
                    for (int r = 0; r < 4; ++r)
                        lmax[r] = fmaxf(lmax[r], sv[f][r]);
            }

            // defer-max: reduce+rescale only if some row grew past m_old+8
            float dmax = fmaxf(fmaxf(lmax[0], lmax[1]), fmaxf(lmax[2], lmax[3]));
            if (!__all(dmax <= 8.0f)) {
                float tmax[4] = {lmax[0], lmax[1], lmax[2], lmax[3]};
#pragma unroll
                for (int off = 1; off < 16; off <<= 1)
#pragma unroll
                    for (int r = 0; r < 4; ++r)
                        tmax[r] = fmaxf(tmax[r], __shfl_xor(tmax[r], off, 64));
#pragma unroll
                for (int r = 0; r < 4; ++r) {
                    float d = fmaxf(tmax[r], 0.f);
                    float alpha = exp2f(-d);
                    m_st[r] += d;
                    acc_l[r] *= alpha;
#pragma unroll
                    for (int f = 0; f < 4; ++f) {
                        acc[f][r] *= alpha;
                        sv[f][r] -= d;
                    }
                }
            }

            // P = exp2(sv); write bf16 P to wave-private LDS (swizzled)
#pragma unroll
            for (int f = 0; f < 4; ++f)
#pragma unroll
                for (int r = 0; r < 4; ++r) {
                    float p = exp2f(sv[f][r]);
                    int prow = 4 * lr + r, pcol = 16 * f + lc;
                    Ps[w][prow * 64 + (((pcol >> 3) ^ (prow & 7)) * 8) + (pcol & 7)] = f2bf(p);
                }

            // PV + ones-column l accumulation (all on matrix pipe)
            __builtin_amdgcn_s_setprio(1);
#pragma unroll
            for (int kk = 0; kk < 2; ++kk) {
                bf16x8 pf = *(const bf16x8*)&Ps[w][lc * 64 + (((lr + 4 * kk) ^ (lc & 7)) * 8)];
                acc_l = mfma16(pf, ones, acc_l);
#pragma unroll
                for (int f = 0; f < 4; ++f) {
                    int vrow = 16 * f + lc;
                    bf16x8 vfr = *(const bf16x8*)&Vs[cur][vrow * 64 + (((lr + 4 * kk) ^ (vrow & 7)) * 8)];
                    acc[f] = mfma16(pf, vfr, acc[f]);
                }
            }
            __builtin_amdgcn_s_setprio(0);

            asm volatile("s_waitcnt vmcnt(0)" ::: "memory");
            __builtin_amdgcn_s_barrier();
        }

        // normalize (acc_l[r] = full row sum in every lane) + store
        float inv[4];
#pragma unroll
        for (int r = 0; r < 4; ++r) inv[r] = 1.f / acc_l[r];
#pragma unroll
        for (int f = 0; f < 4; ++f)
#pragma unroll
            for (int r = 0; r < 4; ++r) {
                int t = qt * 64 + w * 16 + 4 * lr + r;
                attnb[((size_t)(b * T_ + t)) * 1024 + h * 64 + 16 * f + lc] =
                    f2bf(acc[f][r] * inv[r]);
            }
    }
}

extern "C" void kernel_launch(void* const* d_in, const int* in_sizes, int n_in,
                              void* d_out, int out_size, void* d_ws, size_t ws_size,
                              hipStream_t stream) {
    const float* hs     = (const float*)d_in[0];
    const float* cosp   = (const float*)d_in[1];
    const float* sinp   = (const float*)d_in[2];
    const float* qkv_w  = (const float*)d_in[3];
    const float* qkv_b  = (const float*)d_in[4];
    const float* proj_w = (const float*)d_in[5];
    const float* proj_b = (const float*)d_in[6];
    float* out = (float*)d_out;

    const int M = B_ * T_;            // 4096
    ushort_t* Xb     = (ushort_t*)d_ws;
    ushort_t* Wqkvb  = Xb + (size_t)M * C_;
    ushort_t* Wprojb = Wqkvb + (size_t)3072 * C_;
    ushort_t* QKV    = Wprojb + (size_t)C_ * C_;
    ushort_t* Qr     = QKV + (size_t)M * 3072;
    ushort_t* Kr     = Qr + (size_t)B_ * H_ * T_ * D_;
    ushort_t* Vt     = Kr + (size_t)B_ * H_ * T_ * D_;
    ushort_t* attnb  = Vt + (size_t)B_ * H_ * T_ * D_;

    cvt3_kernel<<<2048, 256, 0, stream>>>(hs, Xb, M * C_,
                                          qkv_w, Wqkvb, 3072 * C_,
                                          proj_w, Wprojb, C_ * C_);

    gemm_bt<1><<<768, 256, 0, stream>>>(
        Xb, Wqkvb, qkv_b, QKV, nullptr, M, 3072, C_, 3072 / 128);

    rope_scatter<<<B_ * H_ * (T_ / 64), 256, 0, stream>>>(QKV, cosp, sinp, Qr, Kr, Vt);

    attn_kernel<<<512, 256, 0, stream>>>(Qr, Kr, Vt, attnb);

    gemm_bt<0><<<256, 256, 0, stream>>>(
        attnb, Wprojb, proj_b, nullptr, out, M, C_, C_, 1024 / 128);
}

// Round 6
// 128.507 us; speedup vs baseline: 1.6768x; 1.0759x over previous
//
#include <hip/hip_runtime.h>
#include <stdint.h>

#define B_ 2
#define T_ 2048
#define C_ 1024
#define H_ 16
#define D_ 64
// SCALE * log2(e): softmax computed in exp2 domain; folded into Q at rope time
#define SCALE_L2E 0.1803368801111244f

typedef unsigned short ushort_t;
typedef __attribute__((ext_vector_type(8))) __bf16 bf16x8;
typedef __attribute__((ext_vector_type(4))) float f32x4;
typedef __attribute__((ext_vector_type(4))) unsigned short ushort4_t;

__device__ __forceinline__ float bf2f(ushort_t u) {
    union { unsigned int u; float f; } v; v.u = ((unsigned int)u) << 16; return v.f;
}
// native f32->bf16 (compiler emits v_cvt_pk_bf16_f32, RNE)
__device__ __forceinline__ ushort_t f2bf(float f) {
    union { __bf16 h; ushort_t u; } v; v.h = (__bf16)f; return v.u;
}

__device__ __forceinline__ void gl16(const void* g, void* l) {
    __builtin_amdgcn_global_load_lds(
        (const __attribute__((address_space(1))) void*)g,
        (__attribute__((address_space(3))) void*)l, 16, 0, 0);
}

__device__ __forceinline__ f32x4 mfma16(bf16x8 a, bf16x8 b, f32x4 c) {
    return __builtin_amdgcn_mfma_f32_16x16x32_bf16(a, b, c, 0, 0, 0);
}

// ---------------- fused fp32 -> bf16 convert (3 tensors) ----------------
__global__ __launch_bounds__(256) void cvt3_kernel(const float* __restrict__ a, ushort_t* __restrict__ oa, int na,
                                                   const float* __restrict__ b, ushort_t* __restrict__ ob, int nb,
                                                   const float* __restrict__ c, ushort_t* __restrict__ oc, int nc) {
    int total4 = (na + nb + nc) >> 2;
    int stride = gridDim.x * blockDim.x;
    for (int i = blockIdx.x * blockDim.x + threadIdx.x; i < total4; i += stride) {
        int e = i << 2;
        const float* src; ushort_t* dst; int off;
        if (e < na) { src = a; dst = oa; off = e; }
        else if (e < na + nb) { src = b; dst = ob; off = e - na; }
        else { src = c; dst = oc; off = e - na - nb; }
        float4 v = *(const float4*)(src + off);
        ushort4_t o;
        o.x = f2bf(v.x); o.y = f2bf(v.y); o.z = f2bf(v.z); o.w = f2bf(v.w);
        *(ushort4_t*)(dst + off) = o;
    }
}

// ---------------- GEMM (proj): C[M,N] = A[M,K]*B[N,K]^T + bias, fp32 out ----------------
// 2-phase double-buffered staging; 1-D grid with bijective XCD swizzle.
__global__ __launch_bounds__(256) void gemm_proj(const ushort_t* __restrict__ A,
                                                 const ushort_t* __restrict__ Bw,
                                                 const float* __restrict__ bias,
                                                 float* __restrict__ outf,
                                                 int M, int N, int K, int nxt) {
    int q = gridDim.x >> 3;
    int nid = (blockIdx.x & 7) * q + (blockIdx.x >> 3);
    int bx = nid % nxt, by = nid / nxt;

    __shared__ ushort_t sm[16384];   // 2 bufs x (As 4096 + Bs 4096)
    int tid = threadIdx.x, w = tid >> 6, lane = tid & 63;
    int lr = lane >> 4, lc = lane & 15;
    int wr = w >> 1, wc = w & 1;
    int row0 = by * 128, col0 = bx * 128;

    f32x4 acc[4][4];
#pragma unroll
    for (int mf = 0; mf < 4; ++mf)
#pragma unroll
        for (int nf = 0; nf < 4; ++nf) acc[mf][nf] = (f32x4){0.f, 0.f, 0.f, 0.f};

    auto stageg = [&](int buf, int k0) {
#pragma unroll
        for (int j = 0; j < 2; ++j) {
            int idx = j * 256 + tid;
            int r = idx >> 2, c = (idx & 3) * 8;
            gl16(A + (size_t)(row0 + r) * K + k0 + c, &sm[buf * 8192 + idx * 8]);
            gl16(Bw + (size_t)(col0 + r) * K + k0 + c, &sm[buf * 8192 + 4096 + idx * 8]);
        }
    };

    stageg(0, 0);
    asm volatile("s_waitcnt vmcnt(0)" ::: "memory");
    __builtin_amdgcn_s_barrier();

    for (int k0 = 0; k0 < K; k0 += 32) {
        int cur = (k0 >> 5) & 1;
        if (k0 + 32 < K) stageg(cur ^ 1, k0 + 32);
        const ushort_t* As = &sm[cur * 8192];
        const ushort_t* Bs = &sm[cur * 8192 + 4096];
        bf16x8 af[4], bfr[4];
#pragma unroll
        for (int mf = 0; mf < 4; ++mf)
            af[mf] = *(const bf16x8*)&As[(wr * 64 + mf * 16 + lc) * 32 + 8 * lr];
#pragma unroll
        for (int nf = 0; nf < 4; ++nf)
            bfr[nf] = *(const bf16x8*)&Bs[(wc * 64 + nf * 16 + lc) * 32 + 8 * lr];
        __builtin_amdgcn_s_setprio(1);
#pragma unroll
        for (int mf = 0; mf < 4; ++mf)
#pragma unroll
            for (int nf = 0; nf < 4; ++nf)
                acc[mf][nf] = mfma16(af[mf], bfr[nf], acc[mf][nf]);
        __builtin_amdgcn_s_setprio(0);
        asm volatile("s_waitcnt vmcnt(0)" ::: "memory");
        __builtin_amdgcn_s_barrier();
    }
#pragma unroll
    for (int mf = 0; mf < 4; ++mf)
#pragma unroll
        for (int nf = 0; nf < 4; ++nf) {
            int col = col0 + wc * 64 + nf * 16 + lc;
            float bv = bias[col];
#pragma unroll
            for (int r = 0; r < 4; ++r) {
                int row = row0 + wr * 64 + mf * 16 + 4 * lr + r;
                outf[(size_t)row * N + col] = acc[mf][nf][r] + bv;
            }
        }
}

// ---------------- GEMM1 fused: QKV = X*Wqkv^T + b, + RoPE + scatter ----------------
// M=4096, N=3072, K=1024, grid 768. bx<8: Q (rope+scale), bx<16: K (rope),
// bx>=16: V (LDS-transpose -> Vt[bh][64][2048]).
__global__ __launch_bounds__(256) void gemm_qkv_rope(const ushort_t* __restrict__ A,
                                                     const ushort_t* __restrict__ Bw,
                                                     const float* __restrict__ bias,
                                                     const float* __restrict__ cosT,
                                                     const float* __restrict__ sinT,
                                                     ushort_t* __restrict__ Qr,
                                                     ushort_t* __restrict__ Kr,
                                                     ushort_t* __restrict__ Vt) {
    const int K = 1024;
    int nid = (blockIdx.x & 7) * 96 + (blockIdx.x >> 3);
    int bx = nid % 24, by = nid / 24;

    __shared__ ushort_t sm[16384];   // dbuf staging; aliased as V-transpose tile after K-loop
    int tid = threadIdx.x, w = tid >> 6, lane = tid & 63;
    int lr = lane >> 4, lc = lane & 15;
    int wr = w >> 1, wc = w & 1;
    int row0 = by * 128, col0 = bx * 128;

    f32x4 acc[4][4];
#pragma unroll
    for (int mf = 0; mf < 4; ++mf)
#pragma unroll
        for (int nf = 0; nf < 4; ++nf) acc[mf][nf] = (f32x4){0.f, 0.f, 0.f, 0.f};

    auto stageg = [&](int buf, int k0) {
#pragma unroll
        for (int j = 0; j < 2; ++j) {
            int idx = j * 256 + tid;
            int r = idx >> 2, c = (idx & 3) * 8;
            gl16(A + (size_t)(row0 + r) * K + k0 + c, &sm[buf * 8192 + idx * 8]);
            gl16(Bw + (size_t)(col0 + r) * K + k0 + c, &sm[buf * 8192 + 4096 + idx * 8]);
        }
    };

    stageg(0, 0);
    asm volatile("s_waitcnt vmcnt(0)" ::: "memory");
    __builtin_amdgcn_s_barrier();

    for (int k0 = 0; k0 < K; k0 += 32) {
        int cur = (k0 >> 5) & 1;
        if (k0 + 32 < K) stageg(cur ^ 1, k0 + 32);
        const ushort_t* As = &sm[cur * 8192];
        const ushort_t* Bs = &sm[cur * 8192 + 4096];
        bf16x8 af[4], bfr[4];
#pragma unroll
        for (int mf = 0; mf < 4; ++mf)
            af[mf] = *(const bf16x8*)&As[(wr * 64 + mf * 16 + lc) * 32 + 8 * lr];
#pragma unroll
        for (int nf = 0; nf < 4; ++nf)
            bfr[nf] = *(const bf16x8*)&Bs[(wc * 64 + nf * 16 + lc) * 32 + 8 * lr];
        __builtin_amdgcn_s_setprio(1);
#pragma unroll
        for (int mf = 0; mf < 4; ++mf)
#pragma unroll
            for (int nf = 0; nf < 4; ++nf)
                acc[mf][nf] = mfma16(af[mf], bfr[nf], acc[mf][nf]);
        __builtin_amdgcn_s_setprio(0);
        asm volatile("s_waitcnt vmcnt(0)" ::: "memory");
        __builtin_amdgcn_s_barrier();
    }

    if (bx < 16) {
        // ---- Q / K epilogue with RoPE ----
        const int typ = bx >> 3;                 // 0 = Q, 1 = K
        ushort_t* dstb = typ ? Kr : Qr;
#pragma unroll
        for (int nf = 0; nf < 4; ++nf) {
            int fullc = col0 + wc * 64 + nf * 16 + lc;
            int gc = fullc & 1023;
            int h = gc >> 6;
            int d2 = (gc & 63) >> 1;
            int odd = gc & 1;
            float bv = bias[fullc];
#pragma unroll
            for (int mf = 0; mf < 4; ++mf)
#pragma unroll
                for (int r = 0; r < 4; ++r) {
                    int row = row0 + wr * 64 + mf * 16 + 4 * lr + r;
                    int bb = row >> 11, t = row & 2047;
                    float v = acc[mf][nf][r] + bv;
                    float pv = __shfl_xor(v, 1, 64);   // partner column (2d2 <-> 2d2+1)
                    float cth = cosT[t * 32 + d2], sth = sinT[t * 32 + d2];
                    float o = odd ? (pv * sth + v * cth) : (v * cth - pv * sth);
                    if (typ == 0) o *= SCALE_L2E;
                    int od = odd ? (d2 + 32) : d2;
                    dstb[((size_t)(bb * H_ + h) * T_ + t) * D_ + od] = f2bf(o);
                }
        }
    } else {
        // ---- V epilogue: transpose 128t x 64c half-tiles through LDS ----
        int bb = row0 >> 11;
        int tb = row0 & 2047;
#pragma unroll 1
        for (int half = 0; half < 2; ++half) {
            __syncthreads();
            if (wc == half) {
#pragma unroll
                for (int nf = 0; nf < 4; ++nf) {
                    int fullc = col0 + wc * 64 + nf * 16 + lc;
                    float bv = bias[fullc];
                    int c = nf * 16 + lc;     // 0..63 within this head
#pragma unroll
                    for (int mf = 0; mf < 4; ++mf)
#pragma unroll
                        for (int r = 0; r < 4; ++r) {
                            int tl = wr * 64 + mf * 16 + 4 * lr + r;
                            sm[c * 136 + tl] = f2bf(acc[mf][nf][r] + bv);
                        }
                }
            }
            __syncthreads();
            int h = ((bx - 16) << 1) + half;
#pragma unroll
            for (int it = 0; it < 8; ++it) {
                int idx = it * 256 + tid;
                int c = idx >> 5, j = idx & 31;
                ushort4_t vv = *(const ushort4_t*)&sm[c * 136 + 4 * j];
                *(ushort4_t*)&Vt[((size_t)(bb * H_ + h) * D_ + c) * T_ + tb + 4 * j] = vv;
            }
        }
    }
}

// ---------------- causal flash attention, staged + dbuf, paired q-tiles ----------------
// grid: 512 blocks (id = i*32 + bh); block does q-tile i then 31-i => 33 kv-iters.
// l via ones-column MFMA; -m folded into QK acc init; defer-max (THR=8, exp2 dom).
__global__ __launch_bounds__(256) void attn_kernel(const ushort_t* __restrict__ Qr,
                                                   const ushort_t* __restrict__ Kr,
                                                   const ushort_t* __restrict__ Vt,
                                                   ushort_t* __restrict__ attnb) {
    int id = blockIdx.x;
    int bh = id & 31;
    int i_ = id >> 5;
    int b = bh >> 4, h = bh & 15;

    const ushort_t* Qp = Qr + (size_t)bh * T_ * D_;
    const ushort_t* Kp = Kr + (size_t)bh * T_ * D_;
    const ushort_t* Vp = Vt + (size_t)bh * D_ * T_;
    int tid = threadIdx.x, w = tid >> 6, lane = tid & 63;
    int lr = lane >> 4, lc = lane & 15;

    __shared__ ushort_t Ks[2][64 * 64];
    __shared__ ushort_t Vs[2][64 * 64];
    __shared__ ushort_t Ps[4][16 * 64];

    bf16x8 ones;
#pragma unroll
    for (int i = 0; i < 8; ++i) ones[i] = (__bf16)1.0f;

    auto stage = [&](int buf, int kt) {
        int t0 = kt * 64;
#pragma unroll
        for (int j = 0; j < 2; ++j) {
            int idx = j * 256 + tid;
            int row = idx >> 3, ch = idx & 7;
            int sch = ch ^ (row & 7);
            gl16(Kp + (size_t)(t0 + row) * D_ + sch * 8, &Ks[buf][idx * 8]);
            gl16(Vp + (size_t)row * T_ + t0 + sch * 8, &Vs[buf][idx * 8]);
        }
    };

#pragma unroll 1
    for (int pass = 0; pass < 2; ++pass) {
        int qt = pass ? (31 - i_) : i_;

        int qrow = qt * 64 + w * 16 + lc;
        bf16x8 qf0 = *(const bf16x8*)(Qp + (size_t)qrow * D_ + 8 * lr);
        bf16x8 qf1 = *(const bf16x8*)(Qp + (size_t)qrow * D_ + 32 + 8 * lr);

        float m_st[4];
        f32x4 acc[4], acc_l;
#pragma unroll
        for (int r = 0; r < 4; ++r) m_st[r] = 0.f;
#pragma unroll
        for (int f = 0; f < 4; ++f) acc[f] = (f32x4){0.f, 0.f, 0.f, 0.f};
        acc_l = (f32x4){0.f, 0.f, 0.f, 0.f};

        int qg = qt * 64 + w * 16 + 4 * lr;

        stage(0, 0);
        asm volatile("s_waitcnt vmcnt(0)" ::: "memory");
        __builtin_amdgcn_s_barrier();

        for (int kt = 0; kt <= qt; ++kt) {
            int cur = kt & 1;
            if (kt < qt) stage(cur ^ 1, kt + 1);
            int t0 = kt * 64;

            f32x4 neg_m = (f32x4){-m_st[0], -m_st[1], -m_st[2], -m_st[3]};
            f32x4 sv[4];
            __builtin_amdgcn_s_setprio(1);
#pragma unroll
            for (int f = 0; f < 4; ++f) {
                sv[f] = neg_m;
                int row = 16 * f + lc;
#pragma unroll
                for (int kk = 0; kk < 2; ++kk) {
                    bf16x8 kf = *(const bf16x8*)&Ks[cur][row * 64 + (((lr + 4 * kk) ^ (row & 7)) * 8)];
                    sv[f] = mfma16(kk ? qf1 : qf0, kf, sv[f]);
                }
            }
            __builtin_amdgcn_s_setprio(0);

            float lmax[4] = {-1e30f, -1e30f, -1e30f, -1e30f};
            if (kt == qt) {
#pragma unroll
                for (int f = 0; f < 4; ++f) {
                    int kcol = t0 + 16 * f + lc;
#pragma unroll
                    for (int r = 0; r < 4; ++r) {
                        float v = sv[f][r];
                        v = (kcol > qg + r) ? -1e30f : v;
                        sv[f][r] = v;
                        lmax[r] = fmaxf(lmax[r], v);
                    }
                }
            } else {
#pragma unroll
                for (int f = 0; f < 4; ++f)
#pragma unroll
                    for (int r = 0; r < 4; ++r)
                        lmax[r] = fmaxf(lmax[r], sv[f][r]);
            }

            float dmax = fmaxf(fmaxf(lmax[0], lmax[1]), fmaxf(lmax[2], lmax[3]));
            if (!__all(dmax <= 8.0f)) {
                float tmax[4] = {lmax[0], lmax[1], lmax[2], lmax[3]};
#pragma unroll
                for (int off = 1; off < 16; off <<= 1)
#pragma unroll
                    for (int r = 0; r < 4; ++r)
                        tmax[r] = fmaxf(tmax[r], __shfl_xor(tmax[r], off, 64));
#pragma unroll
                for (int r = 0; r < 4; ++r) {
                    float d = fmaxf(tmax[r], 0.f);
                    float alpha = exp2f(-d);
                    m_st[r] += d;
                    acc_l[r] *= alpha;
#pragma unroll
                    for (int f = 0; f < 4; ++f) {
                        acc[f][r] *= alpha;
                        sv[f][r] -= d;
                    }
                }
            }

#pragma unroll
            for (int f = 0; f < 4; ++f)
#pragma unroll
                for (int r = 0; r < 4; ++r) {
                    float p = exp2f(sv[f][r]);
                    int prow = 4 * lr + r, pcol = 16 * f + lc;
                    Ps[w][prow * 64 + (((pcol >> 3) ^ (prow & 7)) * 8) + (pcol & 7)] = f2bf(p);
                }

            __builtin_amdgcn_s_setprio(1);
#pragma unroll
            for (int kk = 0; kk < 2; ++kk) {
                bf16x8 pf = *(const bf16x8*)&Ps[w][lc * 64 + (((lr + 4 * kk) ^ (lc & 7)) * 8)];
                acc_l = mfma16(pf, ones, acc_l);
#pragma unroll
                for (int f = 0; f < 4; ++f) {
                    int vrow = 16 * f + lc;
                    bf16x8 vfr = *(const bf16x8*)&Vs[cur][vrow * 64 + (((lr + 4 * kk) ^ (vrow & 7)) * 8)];
                    acc[f] = mfma16(pf, vfr, acc[f]);
                }
            }
            __builtin_amdgcn_s_setprio(0);

            asm volatile("s_waitcnt vmcnt(0)" ::: "memory");
            __builtin_amdgcn_s_barrier();
        }

        float inv[4];
#pragma unroll
        for (int r = 0; r < 4; ++r) inv[r] = 1.f / acc_l[r];
#pragma unroll
        for (int f = 0; f < 4; ++f)
#pragma unroll
            for (int r = 0; r < 4; ++r) {
                int t = qt * 64 + w * 16 + 4 * lr + r;
                attnb[((size_t)(b * T_ + t)) * 1024 + h * 64 + 16 * f + lc] =
                    f2bf(acc[f][r] * inv[r]);
            }
    }
}

extern "C" void kernel_launch(void* const* d_in, const int* in_sizes, int n_in,
                              void* d_out, int out_size, void* d_ws, size_t ws_size,
                              hipStream_t stream) {
    const float* hs     = (const float*)d_in[0];
    const float* cosp   = (const float*)d_in[1];
    const float* sinp   = (const float*)d_in[2];
    const float* qkv_w  = (const float*)d_in[3];
    const float* qkv_b  = (const float*)d_in[4];
    const float* proj_w = (const float*)d_in[5];
    const float* proj_b = (const float*)d_in[6];
    float* out = (float*)d_out;

    const int M = B_ * T_;            // 4096
    ushort_t* Xb     = (ushort_t*)d_ws;
    ushort_t* Wqkvb  = Xb + (size_t)M * C_;
    ushort_t* Wprojb = Wqkvb + (size_t)3072 * C_;
    ushort_t* Qr     = Wprojb + (size_t)C_ * C_;
    ushort_t* Kr     = Qr + (size_t)B_ * H_ * T_ * D_;
    ushort_t* Vt     = Kr + (size_t)B_ * H_ * T_ * D_;
    ushort_t* attnb  = Vt + (size_t)B_ * H_ * T_ * D_;

    cvt3_kernel<<<2048, 256, 0, stream>>>(hs, Xb, M * C_,
                                          qkv_w, Wqkvb, 3072 * C_,
                                          proj_w, Wprojb, C_ * C_);

    gemm_qkv_rope<<<768, 256, 0, stream>>>(Xb, Wqkvb, qkv_b, cosp, sinp, Qr, Kr, Vt);

    attn_kernel<<<512, 256, 0, stream>>>(Qr, Kr, Vt, attnb);

    gemm_proj<<<256, 256, 0, stream>>>(attnb, Wprojb, proj_b, out, M, C_, C_, 1024 / 128);
}